// Round 4
// baseline (140.114 us; speedup 1.0000x reference)
//
#include <hip/hip_runtime.h>
#include <math.h>

#define E_DIM 8
#define S_DIM 4096
#define B_DIM 8
#define NROWS (B_DIM * S_DIM)          // 32768
#define TCH 512                        // t-chunk staged in LDS
#define TSPLIT 4                       // t-splits (chunks per block = 1024/TCH = 2)
#define VSTRIDE 520                    // V^T LDS row stride in halves (16B-aligned, banks spread)

// 0.5 (attention scale 1/sqrt(E/NH)=0.5) * log2(e), folded into Q before f16
// rounding so scores come out of the QK mfma ready for raw exp2.
#define QSCALE 0.72134752044448170f

typedef __attribute__((ext_vector_type(4))) float f4;
typedef __attribute__((ext_vector_type(2))) __fp16 h2;
typedef __attribute__((ext_vector_type(4))) __fp16 h4;
typedef __attribute__((ext_vector_type(8))) __fp16 h8;

union QU { uint2 u; h4 h; };
union H8U { h8 v; h2 p[4]; };

__device__ inline float fast_exp2(float x) {
#if __has_builtin(__builtin_amdgcn_exp2f)
    return __builtin_amdgcn_exp2f(x);
#else
    return exp2f(x);
#endif
}

// Kernel 1: Qh[row] = f16(cos(x@Wq.T+bq+theta)*QSCALE)  (16 B/row);
// Kg[row]  = f16 k[0..7]                                 (16 B/row);
// VTg[batch][e][t] = f16 v  (global V-transpose so attn staging is vector copies).
// 2 threads per row (half = tid>>7 -> wave-uniform): 65536 threads = 1024 waves
// = 1 wave/SIMD chip-wide. Also zeroes the split-k arrival counters (cnt[256])
// so the attn kernel's last-block-reduce starts from 0 (ws is poisoned).
__global__ __launch_bounds__(256) void qkv_kernel(
    const float* __restrict__ x,
    const float* __restrict__ Wq, const float* __restrict__ bq,
    const float* __restrict__ Wk, const float* __restrict__ bk,
    const float* __restrict__ Wv, const float* __restrict__ bv,
    const float* __restrict__ theta,
    uint4* __restrict__ Qh, uint4* __restrict__ Kg, __fp16* __restrict__ VTg,
    int* __restrict__ cnt)
{
    int tid = threadIdx.x;
    if (tid == 0) cnt[blockIdx.x] = 0;           // 256 blocks -> 256 counters
    int half = tid >> 7;                         // which 4 of 8 outputs
    int row = blockIdx.x * 128 + (tid & 127);
    const float4* x4 = (const float4*)(x + (size_t)row * E_DIM);
    float4 xa = x4[0], xb = x4[1];
    float xr[8] = {xa.x, xa.y, xa.z, xa.w, xb.x, xb.y, xb.z, xb.w};

    int ib = half * 4;
    float q[4], k[4], v[4];
#pragma unroll
    for (int ii = 0; ii < 4; ++ii) {
        int i = ib + ii;
        float hq = bq[i], hk = bk[i], hv = bv[i];
#pragma unroll
        for (int j = 0; j < 8; ++j) {
            hq += xr[j] * Wq[i * 8 + j];
            hk += xr[j] * Wk[i * 8 + j];
            hv += xr[j] * Wv[i * 8 + j];
        }
        float th = theta[i];
        q[ii] = __cosf(hq + th) * QSCALE;
        k[ii] = __cosf(hk + th);
        v[ii] = __cosf(hv + th);
    }

    union { uint2 u; __fp16 s[4]; } qp, kp;
#pragma unroll
    for (int ii = 0; ii < 4; ++ii) { qp.s[ii] = (__fp16)q[ii]; kp.s[ii] = (__fp16)k[ii]; }
    ((uint2*)Qh)[(size_t)row * 2 + half] = qp.u;
    ((uint2*)Kg)[(size_t)row * 2 + half] = kp.u;

    int batch = row >> 12;
    int t = row & 4095;
#pragma unroll
    for (int e = 0; e < 4; ++e)     // coalesced across lanes (t contiguous)
        VTg[((size_t)(batch * 8 + ib + e) << 12) + t] = (__fp16)v[e];
}

// Kernel 2: full-MFMA flash attention, 32 rows/wave (2 Q-tiles share every
// K/V fragment read), t-split partials (no rescale needed: scores bounded).
// t processed in permuted order t = ch_base + 32*ds + 8*g + 4*s' + i so one
// ds_read_b128 of V^T feeds a single K=32 PV mfma. V^T LDS row 8 = ones ->
// accumulator col 8 = denominator.
// Split-k tail fused: the last-arriving sp-block for each rb (device-scope
// counter, Guideline 12/16 fences) combines the TSPLIT partials, normalizes,
// and applies the Wc projection — no third kernel.
// grid = (NROWS/128, TSPLIT), block = 256 (4 waves x 32 rows) -> 4 blocks/CU.
__global__ __launch_bounds__(256) void attn_mfma(
    const uint4* __restrict__ Qh, const uint4* __restrict__ Kg,
    const __fp16* __restrict__ VTg,
    float* __restrict__ ACC, float* __restrict__ DEN,
    int* __restrict__ cnt,
    const float* __restrict__ Wc, const float* __restrict__ bc,
    float* __restrict__ out)
{
    __shared__ __align__(16) __fp16 Kpad[TCH * 16];      // 16 KB; e=8..15 zero
    __shared__ __align__(16) __fp16 Vt[16 * VSTRIDE];    // 16.25 KB; row8=1, rows9-15=0
    __shared__ int lastFlag;

    int tid = threadIdx.x;
    int l = tid & 63;
    int wv = tid >> 6;
    int rb = blockIdx.x;               // 0..255 row-groups of 128
    int sp = blockIdx.y;               // t-split 0..3
    int batch = rb >> 5;
    int rbase = rb * 128 + wv * 32;    // wave's 32 global rows

    // one-time constant LDS init (never overwritten by staging):
    for (int r = tid; r < TCH; r += 256)                       // K rows e=8..15 = 0
        *((uint4*)(Kpad + r * 16 + 8)) = make_uint4(0, 0, 0, 0);
    {
        uint* z = (uint*)(Vt + 9 * VSTRIDE);                   // Vt rows 9..15 = 0
        for (int i = tid; i < 7 * VSTRIDE / 2; i += 256) z[i] = 0;
        uint* o1 = (uint*)(Vt + 8 * VSTRIDE);                  // Vt row 8 = 1.0
        for (int i = tid; i < VSTRIDE / 2; i += 256) o1[i] = 0x3C003C00u;
    }

    // Q fragments (loop-invariant): B[k=e][n=r]; lanes 32..63 give e>=8 -> 0
    QU q0u, q1u; q0u.u = make_uint2(0, 0); q1u.u = make_uint2(0, 0);
    if ((l >> 4) < 2) {
        const uint2* Q2 = (const uint2*)Qh;
        q0u.u = Q2[(size_t)(rbase + (l & 15)) * 2 + (l >> 4)];
        q1u.u = Q2[(size_t)(rbase + 16 + (l & 15)) * 2 + (l >> 4)];
    }
    h4 qf0 = q0u.h, qf1 = q1u.h;

    // per-lane fragment base pointers (hoisted out of the ds loop)
    int koff = ((l & 12) << 1) + (l & 3);            // 8*((l&15)>>2) + (l&3)
    const __fp16* kbase = Kpad + (koff << 4) + ((l >> 4) << 2); // + ds*512, +64 for kf1
    const __fp16* vbase = Vt + (l & 15) * VSTRIDE + ((l >> 4) << 3); // + ds*32

    f4 C0 = {0.f, 0.f, 0.f, 0.f};
    f4 C1 = {0.f, 0.f, 0.f, 0.f};

    for (int ch = 0; ch < 1024 / TCH; ++ch) {
        int tb = sp * 1024 + ch * TCH;               // chunk base t within batch
        __syncthreads();                             // covers init / prev compute
        // stage K: 512 rows x 16 B
        {
            const uint4* src = Kg + ((size_t)batch << 12) + tb;
            for (int i = tid; i < TCH; i += 256)
                *((uint4*)(Kpad + i * 16)) = src[i];
        }
        // stage V^T: 8 rows x 512 halves (vector copies, no scatter)
        {
            for (int i = tid; i < 8 * (TCH / 8); i += 256) {   // 512 uint4
                int e = i >> 6, c = i & 63;
                const uint4* src = (const uint4*)(VTg + (((size_t)(batch * 8 + e)) << 12) + tb);
                *((uint4*)(Vt + e * VSTRIDE + c * 8)) = src[c];
            }
        }
        __syncthreads();

#pragma unroll 4
        for (int ds = 0; ds < TCH / 32; ++ds) {      // 16 double-steps of 32 t
            h4 kf0 = *((const h4*)(kbase + ds * 512));
            h4 kf1 = *((const h4*)(kbase + ds * 512 + 64));
            h8 vr  = *((const h8*)(vbase + ds * 32));

            f4 z = {0.f, 0.f, 0.f, 0.f};
            f4 s00 = __builtin_amdgcn_mfma_f32_16x16x16f16(kf0, qf0, z, 0, 0, 0);
            f4 s01 = __builtin_amdgcn_mfma_f32_16x16x16f16(kf1, qf0, z, 0, 0, 0);
            f4 s10 = __builtin_amdgcn_mfma_f32_16x16x16f16(kf0, qf1, z, 0, 0, 0);
            f4 s11 = __builtin_amdgcn_mfma_f32_16x16x16f16(kf1, qf1, z, 0, 0, 0);

            // exp2 then packed f32->f16 converts (pkrtz: RTZ; denominator is the
            // sum of the SAME rounded P values, so rounding cancels in the ratio).
            f4 e00, e01, e10, e11;
#pragma unroll
            for (int i = 0; i < 4; ++i) {
                e00[i] = fast_exp2(s00[i]);
                e01[i] = fast_exp2(s01[i]);
                e10[i] = fast_exp2(s10[i]);
                e11[i] = fast_exp2(s11[i]);
            }
            H8U pa0, pa1;
            pa0.p[0] = __builtin_amdgcn_cvt_pkrtz(e00[0], e00[1]);
            pa0.p[1] = __builtin_amdgcn_cvt_pkrtz(e00[2], e00[3]);
            pa0.p[2] = __builtin_amdgcn_cvt_pkrtz(e01[0], e01[1]);
            pa0.p[3] = __builtin_amdgcn_cvt_pkrtz(e01[2], e01[3]);
            pa1.p[0] = __builtin_amdgcn_cvt_pkrtz(e10[0], e10[1]);
            pa1.p[1] = __builtin_amdgcn_cvt_pkrtz(e10[2], e10[3]);
            pa1.p[2] = __builtin_amdgcn_cvt_pkrtz(e11[0], e11[1]);
            pa1.p[3] = __builtin_amdgcn_cvt_pkrtz(e11[2], e11[3]);

            // {p00,p01} is exactly the K=32 A-fragment (k = 8*(l>>4)+j); vr is
            // exactly the K=32 B-fragment -> one 16x16x32 mfma per C tile.
            C0 = __builtin_amdgcn_mfma_f32_16x16x32_f16(pa0.v, vr, C0, 0, 0, 0);
            C1 = __builtin_amdgcn_mfma_f32_16x16x32_f16(pa1.v, vr, C1, 0, 0, 0);
        }
    }

    // C: lane l reg i = Onum[row 4*(l>>4)+i][e=l&15]; col 8 = denominator.
    int e = l & 15;
    int g = l >> 4;
#pragma unroll
    for (int i = 0; i < 4; ++i) {
        int r0 = rbase + 4 * g + i;
        if (e < 8) {
            ACC[(((size_t)sp * NROWS + r0) << 3) + e] = C0[i];
            ACC[(((size_t)sp * NROWS + r0 + 16) << 3) + e] = C1[i];
        } else if (e == 8) {
            DEN[(size_t)sp * NROWS + r0] = C0[i];
            DEN[(size_t)sp * NROWS + r0 + 16] = C1[i];
        }
    }

    // ---- fused split-k tail: last sp-block for this rb finalizes 128 rows ----
    __syncthreads();                   // drains all partial stores (vmcnt 0)
    if (tid == 0) {
        __threadfence();               // release: partials visible device-wide
        lastFlag = (atomicAdd(&cnt[rb], 1) == TSPLIT - 1);
    }
    __syncthreads();
    if (lastFlag) {
        __threadfence();               // acquire: see all other blocks' partials
        if (tid < 128) {
            int row = rb * 128 + tid;
            float a[8] = {0,0,0,0,0,0,0,0};
            float den = 0.f;
#pragma unroll
            for (int s2 = 0; s2 < TSPLIT; ++s2) {
                const float4* A4 = (const float4*)(ACC + (((size_t)s2 * NROWS + row) << 3));
                float4 p0 = A4[0], p1 = A4[1];
                a[0] += p0.x; a[1] += p0.y; a[2] += p0.z; a[3] += p0.w;
                a[4] += p1.x; a[5] += p1.y; a[6] += p1.z; a[7] += p1.w;
                den += DEN[(size_t)s2 * NROWS + row];
            }
            float inv = 1.0f / den;
#pragma unroll
            for (int j = 0; j < 8; ++j) a[j] *= inv;
            float r[8];
#pragma unroll
            for (int i = 0; i < 8; ++i) {
                float h = bc[i];
#pragma unroll
                for (int j = 0; j < 8; ++j) h += a[j] * Wc[i * 8 + j];
                r[i] = h;
            }
            float4* O4 = (float4*)(out + (size_t)row * 8);
            O4[0] = make_float4(r[0], r[1], r[2], r[3]);
            O4[1] = make_float4(r[4], r[5], r[6], r[7]);
        }
    }
}

extern "C" void kernel_launch(void* const* d_in, const int* in_sizes, int n_in,
                              void* d_out, int out_size, void* d_ws, size_t ws_size,
                              hipStream_t stream) {
    const float* x     = (const float*)d_in[0];
    const float* Wq    = (const float*)d_in[1];
    const float* bq    = (const float*)d_in[2];
    const float* Wk    = (const float*)d_in[3];
    const float* bk    = (const float*)d_in[4];
    const float* Wv    = (const float*)d_in[5];
    const float* bv    = (const float*)d_in[6];
    const float* theta = (const float*)d_in[7];
    const float* Wc    = (const float*)d_in[8];
    const float* bc    = (const float*)d_in[9];
    float* out = (float*)d_out;

    // ws (f32 units): Qh 4/row, Kg 4/row, VTg 4/row, ACC TSPLIT*8/row,
    // DEN TSPLIT/row, cnt 256 ints
    float* ws  = (float*)d_ws;
    uint4*  Qh  = (uint4*)ws;
    uint4*  Kg  = (uint4*)(ws + (size_t)NROWS * 4);
    __fp16* VTg = (__fp16*)(ws + (size_t)NROWS * 8);
    float*  ACC = ws + (size_t)NROWS * 12;
    float*  DEN = ACC + (size_t)TSPLIT * NROWS * 8;
    int*    cnt = (int*)(DEN + (size_t)TSPLIT * NROWS);

    qkv_kernel<<<NROWS * 2 / 256, 256, 0, stream>>>(x, Wq, bq, Wk, bk, Wv, bv, theta,
                                                    Qh, Kg, VTg, cnt);

    dim3 grid2(NROWS / 128, TSPLIT);   // (256, 4)
    attn_mfma<<<grid2, 256, 0, stream>>>(Qh, Kg, VTg, ACC, DEN, cnt, Wc, bc, out);
}

// Round 5
// 98.126 us; speedup vs baseline: 1.4279x; 1.4279x over previous
//
#include <hip/hip_runtime.h>
#include <math.h>

#define E_DIM 8
#define S_DIM 4096
#define B_DIM 8
#define NROWS (B_DIM * S_DIM)          // 32768
#define TCH 512                        // t-chunk staged in LDS
#define TSPLIT 4                       // t-splits (chunks per block = 1024/TCH = 2)
#define VSTRIDE 520                    // V^T LDS row stride in halves (16B-aligned, banks spread)

// 0.5 (attention scale 1/sqrt(E/NH)=0.5) * log2(e), folded into Q before f16
// rounding so scores come out of the QK mfma ready for raw exp2.
#define QSCALE 0.72134752044448170f

typedef __attribute__((ext_vector_type(4))) float f4;
typedef __attribute__((ext_vector_type(2))) __fp16 h2;
typedef __attribute__((ext_vector_type(4))) __fp16 h4;
typedef __attribute__((ext_vector_type(8))) __fp16 h8;

union QU { uint2 u; h4 h; };
union H8U { h8 v; h2 p[4]; };

__device__ inline float fast_exp2(float x) {
#if __has_builtin(__builtin_amdgcn_exp2f)
    return __builtin_amdgcn_exp2f(x);
#else
    return exp2f(x);
#endif
}

// Kernel 1: Qh[row] = f16(cos(x@Wq.T+bq+theta)*QSCALE)  (16 B/row);
// Kg[row]  = f16 k[0..7]                                 (16 B/row);
// VTg[batch][e][t] = f16 v  (global V-transpose so attn staging is vector copies).
// 2 threads per row (half = tid>>7 -> wave-uniform): 65536 threads = 1024 waves
// = 1 wave/SIMD chip-wide.
__global__ __launch_bounds__(256) void qkv_kernel(
    const float* __restrict__ x,
    const float* __restrict__ Wq, const float* __restrict__ bq,
    const float* __restrict__ Wk, const float* __restrict__ bk,
    const float* __restrict__ Wv, const float* __restrict__ bv,
    const float* __restrict__ theta,
    uint4* __restrict__ Qh, uint4* __restrict__ Kg, __fp16* __restrict__ VTg)
{
    int tid = threadIdx.x;
    int half = tid >> 7;                         // which 4 of 8 outputs
    int row = blockIdx.x * 128 + (tid & 127);
    const float4* x4 = (const float4*)(x + (size_t)row * E_DIM);
    float4 xa = x4[0], xb = x4[1];
    float xr[8] = {xa.x, xa.y, xa.z, xa.w, xb.x, xb.y, xb.z, xb.w};

    int ib = half * 4;
    float q[4], k[4], v[4];
#pragma unroll
    for (int ii = 0; ii < 4; ++ii) {
        int i = ib + ii;
        float hq = bq[i], hk = bk[i], hv = bv[i];
#pragma unroll
        for (int j = 0; j < 8; ++j) {
            hq += xr[j] * Wq[i * 8 + j];
            hk += xr[j] * Wk[i * 8 + j];
            hv += xr[j] * Wv[i * 8 + j];
        }
        float th = theta[i];
        q[ii] = __cosf(hq + th) * QSCALE;
        k[ii] = __cosf(hk + th);
        v[ii] = __cosf(hv + th);
    }

    union { uint2 u; __fp16 s[4]; } qp, kp;
#pragma unroll
    for (int ii = 0; ii < 4; ++ii) { qp.s[ii] = (__fp16)q[ii]; kp.s[ii] = (__fp16)k[ii]; }
    ((uint2*)Qh)[(size_t)row * 2 + half] = qp.u;
    ((uint2*)Kg)[(size_t)row * 2 + half] = kp.u;

    int batch = row >> 12;
    int t = row & 4095;
#pragma unroll
    for (int e = 0; e < 4; ++e)     // coalesced across lanes (t contiguous)
        VTg[((size_t)(batch * 8 + ib + e) << 12) + t] = (__fp16)v[e];
}

// Kernel 2: full-MFMA flash attention, 32 rows/wave (2 Q-tiles share every
// K/V fragment read), t-split partials (no rescale needed: scores bounded).
// t processed in permuted order t = ch_base + 32*ds + 8*g + 4*s' + i so one
// ds_read_b128 of V^T feeds a single K=32 PV mfma. V^T LDS row 8 = ones ->
// accumulator col 8 = denominator.
// Kpad slot-rotation swizzle: each 32B row has 4x8B slots; K data lives at
// slots {rot, rot+1}, rot=(row>>3)&3, zeros elsewhere. Kills the 4-way bank
// conflict of the kf reads (rows 0/8/16/24 previously aliased to one bank set;
// R4 counters: SQ_LDS_BANK_CONFLICT=3.87M). rot is ds-invariant per lane
// ((l>>2)&3), so it folds into kbase and the inner loop is unchanged.
// grid = (NROWS/128, TSPLIT), block = 256 (4 waves x 32 rows) -> 4 blocks/CU.
__global__ __launch_bounds__(256) void attn_mfma(
    const uint4* __restrict__ Qh, const uint4* __restrict__ Kg,
    const __fp16* __restrict__ VTg,
    float* __restrict__ ACC, float* __restrict__ DEN)
{
    __shared__ __align__(16) __fp16 Kpad[TCH * 16];      // 16 KB; zero slots per-row
    __shared__ __align__(16) __fp16 Vt[16 * VSTRIDE];    // 16.25 KB; row8=1, rows9-15=0

    int tid = threadIdx.x;
    int l = tid & 63;
    int wv = tid >> 6;
    int rb = blockIdx.x;               // 0..255 row-groups of 128
    int sp = blockIdx.y;               // t-split 0..3
    int batch = rb >> 5;
    int rbase = rb * 128 + wv * 32;    // wave's 32 global rows

    // one-time LDS init: zero ALL of Kpad (data slots get overwritten by
    // staging each chunk; the row-dependent zero slots must be 0, and LDS is
    // uninitialized -> could hold NaN patterns that poison 0*NaN in the mfma).
    {
        uint4* kz = (uint4*)Kpad;
        for (int i = tid; i < TCH * 2; i += 256) kz[i] = make_uint4(0, 0, 0, 0);
    }
    {
        uint* z = (uint*)(Vt + 9 * VSTRIDE);                   // Vt rows 9..15 = 0
        for (int i = tid; i < 7 * VSTRIDE / 2; i += 256) z[i] = 0;
        uint* o1 = (uint*)(Vt + 8 * VSTRIDE);                  // Vt row 8 = 1.0
        for (int i = tid; i < VSTRIDE / 2; i += 256) o1[i] = 0x3C003C00u;
    }

    // Q fragments (loop-invariant): B[k=e][n=r]; lanes 32..63 give e>=8 -> 0
    QU q0u, q1u; q0u.u = make_uint2(0, 0); q1u.u = make_uint2(0, 0);
    if ((l >> 4) < 2) {
        const uint2* Q2 = (const uint2*)Qh;
        q0u.u = Q2[(size_t)(rbase + (l & 15)) * 2 + (l >> 4)];
        q1u.u = Q2[(size_t)(rbase + 16 + (l & 15)) * 2 + (l >> 4)];
    }
    h4 qf0 = q0u.h, qf1 = q1u.h;

    // per-lane fragment base pointers (hoisted out of the ds loop)
    int koff = ((l & 12) << 1) + (l & 3);            // 8*((l&15)>>2) + (l&3)
    int slot_r = (((l >> 4) + (l >> 2)) & 3);        // (slot + rot) & 3
    const __fp16* kbase = Kpad + (koff << 4) + (slot_r << 2); // + ds*512, +64 for kf1
    const __fp16* vbase = Vt + (l & 15) * VSTRIDE + ((l >> 4) << 3); // + ds*32

    f4 C0 = {0.f, 0.f, 0.f, 0.f};
    f4 C1 = {0.f, 0.f, 0.f, 0.f};

    for (int ch = 0; ch < 1024 / TCH; ++ch) {
        int tb = sp * 1024 + ch * TCH;               // chunk base t within batch
        __syncthreads();                             // covers init / prev compute
        // stage K: 512 rows; data 8B-halves go to rotated slots rot, rot+1
        {
            const uint4* src = Kg + ((size_t)batch << 12) + tb;
            for (int i = tid; i < TCH; i += 256) {
                uint4 kd = src[i];
                int rot = (i >> 3) & 3;
                *((uint2*)(Kpad + i * 16 + (( rot      & 3) << 2))) = make_uint2(kd.x, kd.y);
                *((uint2*)(Kpad + i * 16 + (((rot + 1) & 3) << 2))) = make_uint2(kd.z, kd.w);
            }
        }
        // stage V^T: 8 rows x 512 halves (vector copies, no scatter)
        {
            for (int i = tid; i < 8 * (TCH / 8); i += 256) {   // 512 uint4
                int e = i >> 6, c = i & 63;
                const uint4* src = (const uint4*)(VTg + (((size_t)(batch * 8 + e)) << 12) + tb);
                *((uint4*)(Vt + e * VSTRIDE + c * 8)) = src[c];
            }
        }
        __syncthreads();

#pragma unroll 4
        for (int ds = 0; ds < TCH / 32; ++ds) {      // 16 double-steps of 32 t
            h4 kf0 = *((const h4*)(kbase + ds * 512));
            h4 kf1 = *((const h4*)(kbase + ds * 512 + 64));
            h8 vr  = *((const h8*)(vbase + ds * 32));

            f4 z = {0.f, 0.f, 0.f, 0.f};
            f4 s00 = __builtin_amdgcn_mfma_f32_16x16x16f16(kf0, qf0, z, 0, 0, 0);
            f4 s01 = __builtin_amdgcn_mfma_f32_16x16x16f16(kf1, qf0, z, 0, 0, 0);
            f4 s10 = __builtin_amdgcn_mfma_f32_16x16x16f16(kf0, qf1, z, 0, 0, 0);
            f4 s11 = __builtin_amdgcn_mfma_f32_16x16x16f16(kf1, qf1, z, 0, 0, 0);

            // exp2 then packed f32->f16 converts (pkrtz: RTZ; denominator is the
            // sum of the SAME rounded P values, so rounding cancels in the ratio).
            f4 e00, e01, e10, e11;
#pragma unroll
            for (int i = 0; i < 4; ++i) {
                e00[i] = fast_exp2(s00[i]);
                e01[i] = fast_exp2(s01[i]);
                e10[i] = fast_exp2(s10[i]);
                e11[i] = fast_exp2(s11[i]);
            }
            H8U pa0, pa1;
            pa0.p[0] = __builtin_amdgcn_cvt_pkrtz(e00[0], e00[1]);
            pa0.p[1] = __builtin_amdgcn_cvt_pkrtz(e00[2], e00[3]);
            pa0.p[2] = __builtin_amdgcn_cvt_pkrtz(e01[0], e01[1]);
            pa0.p[3] = __builtin_amdgcn_cvt_pkrtz(e01[2], e01[3]);
            pa1.p[0] = __builtin_amdgcn_cvt_pkrtz(e10[0], e10[1]);
            pa1.p[1] = __builtin_amdgcn_cvt_pkrtz(e10[2], e10[3]);
            pa1.p[2] = __builtin_amdgcn_cvt_pkrtz(e11[0], e11[1]);
            pa1.p[3] = __builtin_amdgcn_cvt_pkrtz(e11[2], e11[3]);

            // {p00,p01} is exactly the K=32 A-fragment (k = 8*(l>>4)+j); vr is
            // exactly the K=32 B-fragment -> one 16x16x32 mfma per C tile.
            C0 = __builtin_amdgcn_mfma_f32_16x16x32_f16(pa0.v, vr, C0, 0, 0, 0);
            C1 = __builtin_amdgcn_mfma_f32_16x16x32_f16(pa1.v, vr, C1, 0, 0, 0);
        }
    }

    // C: lane l reg i = Onum[row 4*(l>>4)+i][e=l&15]; col 8 = denominator.
    int e = l & 15;
    int g = l >> 4;
#pragma unroll
    for (int i = 0; i < 4; ++i) {
        int r0 = rbase + 4 * g + i;
        if (e < 8) {
            ACC[(((size_t)sp * NROWS + r0) << 3) + e] = C0[i];
            ACC[(((size_t)sp * NROWS + r0 + 16) << 3) + e] = C1[i];
        } else if (e == 8) {
            DEN[(size_t)sp * NROWS + r0] = C0[i];
            DEN[(size_t)sp * NROWS + r0 + 16] = C1[i];
        }
    }
}

// Kernel 3: combine t-split partials, normalize, fused Wc projection.
__global__ __launch_bounds__(256) void finalize_kernel(
    const float* __restrict__ ACC, const float* __restrict__ DEN,
    const float* __restrict__ Wc, const float* __restrict__ bc,
    float* __restrict__ out)
{
    int row = blockIdx.x * blockDim.x + threadIdx.x;
    float a[8] = {0,0,0,0,0,0,0,0};
    float den = 0.f;
#pragma unroll
    for (int sp = 0; sp < TSPLIT; ++sp) {
        const float4* A4 = (const float4*)(ACC + (((size_t)sp * NROWS + row) << 3));
        float4 p0 = A4[0], p1 = A4[1];
        a[0] += p0.x; a[1] += p0.y; a[2] += p0.z; a[3] += p0.w;
        a[4] += p1.x; a[5] += p1.y; a[6] += p1.z; a[7] += p1.w;
        den += DEN[(size_t)sp * NROWS + row];
    }
    float inv = 1.0f / den;
#pragma unroll
    for (int j = 0; j < 8; ++j) a[j] *= inv;
    float r[8];
#pragma unroll
    for (int i = 0; i < 8; ++i) {
        float h = bc[i];
#pragma unroll
        for (int j = 0; j < 8; ++j) h += a[j] * Wc[i * 8 + j];
        r[i] = h;
    }
    float4* O4 = (float4*)(out + (size_t)row * 8);
    O4[0] = make_float4(r[0], r[1], r[2], r[3]);
    O4[1] = make_float4(r[4], r[5], r[6], r[7]);
}

extern "C" void kernel_launch(void* const* d_in, const int* in_sizes, int n_in,
                              void* d_out, int out_size, void* d_ws, size_t ws_size,
                              hipStream_t stream) {
    const float* x     = (const float*)d_in[0];
    const float* Wq    = (const float*)d_in[1];
    const float* bq    = (const float*)d_in[2];
    const float* Wk    = (const float*)d_in[3];
    const float* bk    = (const float*)d_in[4];
    const float* Wv    = (const float*)d_in[5];
    const float* bv    = (const float*)d_in[6];
    const float* theta = (const float*)d_in[7];
    const float* Wc    = (const float*)d_in[8];
    const float* bc    = (const float*)d_in[9];
    float* out = (float*)d_out;

    // ws (f32 units): Qh 4/row, Kg 4/row, VTg 4/row, ACC TSPLIT*8/row, DEN TSPLIT/row
    float* ws  = (float*)d_ws;
    uint4*  Qh  = (uint4*)ws;
    uint4*  Kg  = (uint4*)(ws + (size_t)NROWS * 4);
    __fp16* VTg = (__fp16*)(ws + (size_t)NROWS * 8);
    float*  ACC = ws + (size_t)NROWS * 12;
    float*  DEN = ACC + (size_t)TSPLIT * NROWS * 8;
    // total = 32768*(12 + 32 + 4) * 4 B = 6.3 MB

    qkv_kernel<<<NROWS * 2 / 256, 256, 0, stream>>>(x, Wq, bq, Wk, bk, Wv, bv, theta, Qh, Kg, VTg);

    dim3 grid2(NROWS / 128, TSPLIT);   // (256, 4)
    attn_mfma<<<grid2, 256, 0, stream>>>(Qh, Kg, VTg, ACC, DEN);

    finalize_kernel<<<NROWS / 256, 256, 0, stream>>>(ACC, DEN, Wc, bc, out);
}